// Round 20
// baseline (266.465 us; speedup 1.0000x reference)
//
#include <hip/hip_runtime.h>

// LinOSS: damped-oscillator linear SSM scan. B=8, T=2048, H=16, D=64.
//   s = 1-sigmoid(osc_damp); a = DT*exp(osc_w)
//   z' = s*z - a*y + w,  w = DT*beta*k[d]*v[e];  y' = y + DT*z'
//   out = (1/8) q . y
//
// Two-pass chunk-parallel (R19: 263us = L1 80 + L2 176 + overhead).
// R20 rebalance: L1's makespan was pinned by its 256 c0-direct blocks
// (~88us) while 1536 eigen blocks finish in ~40us. Move chunk-0's output
// sweep into L2: L2 = chunks 0..7 = 2048 blocks = EXACTLY 2 residency
// phases (the 256 direct blocks fill what was a 75%-full phase -> same
// makespan, more work). L1 = pure eigen (chunks 0..6, no Q, no dot):
// ~1.75 phases x 40us ~= 70-78us. Bodies are R19's packed-v2f verbatim.

constexpr float DTc = 0.01f;
constexpr int Tn = 2048, Hn = 16, Dn = 64;
constexpr int TS = Hn * Dn; // 1024 floats per t-step in q/k/v/out
constexpr int TILE = 16;

typedef float v2f __attribute__((ext_vector_type(2)));

__device__ __forceinline__ v2f vfma(v2f a, v2f b, v2f c) {
    return __builtin_elementwise_fma(a, b, c);
}

typedef const __attribute__((address_space(1))) void* as1_cvp;
typedef __attribute__((address_space(3))) void* as3_vp;

__device__ __forceinline__ void gload_lds4(const float* g, float* lds) {
    __builtin_amdgcn_global_load_lds((as1_cvp)g, (as3_vp)lds, 4, 0, 0);
}
__device__ __forceinline__ void gload_lds16(const float* g, float* lds) {
    __builtin_amdgcn_global_load_lds((as1_cvp)g, (as3_vp)lds, 16, 0, 0);
}

template<int CTRL>
__device__ __forceinline__ float dpp_add(float x) {
    int yi = __builtin_amdgcn_update_dpp(0, __float_as_int(x), CTRL, 0xF, 0xF, true);
    return x + __int_as_float(yi);
}

// MODE 0 (L1): c = blk>>8 in [0, NC-2]; PURE EIGEN state-only; store ws.
// MODE 1 (L2): c = blk>>8 in [0, NC-1]; c>0 prefix-combine; direct+dot.
template<int NC, int MODE>
__global__ __launch_bounds__(256, 4)
void linoss_k(const float* __restrict__ Q, const float* __restrict__ K,
              const float* __restrict__ V, const float* __restrict__ Bt,
              const float* __restrict__ OW, const float* __restrict__ OD,
              float* __restrict__ Out, float* __restrict__ WS) {
    constexpr int L = Tn / NC;
    constexpr bool DOQ = (MODE == 1);

    __shared__ float sK[2][TILE][64];
    __shared__ float sQ[DOQ ? 2 : 1][DOQ ? TILE : 1][DOQ ? 64 : 1];
    __shared__ float sV[2][TILE][32];
    __shared__ float sB[2][TILE];

    int blk = blockIdx.x;
    int c = blk >> 8;
    int sl = blk & 255;
    // XCD-aware decode: both e-halves of the same (b,h) on one XCD.
    int xcd = sl & 7, slot = sl >> 3;
    int ec = slot & 1;
    int bh = ((slot >> 1) << 3) | xcd;
    int b = bh >> 4, h = bh & 15;

    int tid = threadIdx.x;
    int dgrp = tid & 7;
    int el = tid >> 3;
    int e = ec * 32 + el;
    int d0 = dgrp * 8;
    int wv = tid >> 6;
    int ln = tid & 63;

    v2f y2[4], z2[4];
#pragma unroll
    for (int j = 0; j < 4; ++j) { y2[j] = (v2f)0.0f; z2[j] = (v2f)0.0f; }

    // per-(c,bh,ec) ws tile; quad j layout: {y[2j], y[2j+1], z[2j], z[2j+1]}
    auto wsBase = [&](int ci) {
        return WS + (((size_t)ci * 128 + bh) * 2 + ec) * 4096 + (size_t)tid * 16;
    };

    size_t bhOff = (size_t)b * Tn * TS + (size_t)h * Dn;
    const float* kb0 = K + bhOff;
    const float* qb0 = Q + bhOff;
    const float* vb0 = V + bhOff + ec * 32;
    const float* bb0 = Bt + (size_t)b * Tn * Hn + h;
    float* op = Out + bhOff + e;
    bool wlane = (dgrp == 0);

    int t0 = c * L;

    auto stage = [&](int buf, int tt0) {
        {
            int row = 4 * wv + (ln >> 4);
            gload_lds16(kb0 + (size_t)(tt0 + row) * TS + (ln & 15) * 4, &sK[buf][4 * wv][0]);
        }
        if constexpr (DOQ) {
            int row = 4 * wv + (ln >> 4);
            gload_lds16(qb0 + (size_t)(tt0 + row) * TS + (ln & 15) * 4, &sQ[buf][4 * wv][0]);
        }
        if (wv < 2) {
            int row = 8 * wv + (ln >> 3);
            gload_lds16(vb0 + (size_t)(tt0 + row) * TS + (ln & 7) * 4, &sV[buf][8 * wv][0]);
        }
        if (wv == 2 && ln < 16)
            gload_lds4(bb0 + (size_t)(tt0 + ln) * Hn, &sB[buf][0]);
    };

    constexpr int nT = L / TILE;

    if (MODE == 0) {
        // ---------------- eigen state-only sweep (packed) ----------------
        v2f l12[4], l22[4], mt1[4], mt2[4];
        float l1s[8];
#pragma unroll
        for (int j = 0; j < 4; ++j) {
#pragma unroll
            for (int hlf = 0; hlf < 2; ++hlf) {
                int jj = 2 * j + hlf;
                int idx = (h * Dn + d0 + jj) * Dn + e;
                float aDT = DTc * expf(OW[idx]);
                float s = 1.0f - 1.0f / (1.0f + expf(-OD[idx]));
                float a00 = 1.0f - DTc * aDT, a11 = s;
                float a01 = DTc * s, a10 = -aDT;
                float tr = a00 + a11;
                float dmm = a00 - a11;
                float disc = fmaf(dmm, dmm, 4.0f * a01 * a10);
                float l1 = 0.5f * (tr + sqrtf(disc));
                l1s[jj] = l1;
                l12[j][hlf] = l1;
                l22[j][hlf] = s / l1;   // det = s exactly
            }
            mt1[j] = (v2f)0.0f; mt2[j] = (v2f)0.0f;
        }

        stage(0, t0);
        __syncthreads();
        for (int ti = 0; ti < nT; ++ti) {
            int cur = ti & 1;
            if (ti + 1 < nT) stage(cur ^ 1, t0 + (ti + 1) * TILE);
#pragma unroll 8
            for (int s = 0; s < TILE; ++s) {
                const float4* kr = (const float4*)&sK[cur][s][d0];
                float4 ka = kr[0], kb = kr[1];
                float vv = sV[cur][s][el];
                float bb = sB[cur][s];
                float bv = (DTc * bb) * vv;
                v2f bv2 = {bv, bv};
                v2f kk[4] = {{ka.x, ka.y}, {ka.z, ka.w}, {kb.x, kb.y}, {kb.z, kb.w}};
#pragma unroll
                for (int j = 0; j < 4; ++j) {
                    v2f w = bv2 * kk[j];
                    mt1[j] = vfma(l12[j], mt1[j], w);
                    mt2[j] = vfma(l22[j], mt2[j], w);
                }
            }
            __syncthreads();
        }

        // back-transform to (y,z), packed result
#pragma unroll
        for (int j = 0; j < 4; ++j) {
#pragma unroll
            for (int hlf = 0; hlf < 2; ++hlf) {
                int jj = 2 * j + hlf;
                int idx = (h * Dn + d0 + jj) * Dn + e;
                float aDT = DTc * expf(OW[idx]);
                float s = 1.0f - 1.0f / (1.0f + expf(-OD[idx]));
                float a00 = 1.0f - DTc * aDT, a11 = s;
                float a01 = DTc * s, a10 = -aDT;
                float l1 = l1s[jj], l2 = s / l1;
                float b1 = a01 / (l1 - a11);
                float b2 = (l2 - a00) / a10;
                float c1 = DTc + b1, c2 = DTc + b2;
                float rdb = 1.0f / (b2 - b1);
                float Y1 = b2 * c1 * rdb, Y2 = -b1 * c2 * rdb;
                float Z1 = -c1 * rdb, Z2 = c2 * rdb;
                float m1 = mt1[j][hlf], m2 = mt2[j][hlf];
                y2[j][hlf] = fmaf(Y1, m1, Y2 * m2);
                z2[j][hlf] = fmaf(Z1, m1, Z2 * m2);
            }
        }

        float4* cw = (float4*)wsBase(c);
#pragma unroll
        for (int j = 0; j < 4; ++j) {
            float4 w;
            w.x = y2[j][0]; w.y = y2[j][1];
            w.z = z2[j][0]; w.w = z2[j][1];
            cw[j] = w;
        }
    } else {
        // ---------------- direct sweep with dot (packed) ----------------
        v2f nA2[4], omc2[4];
#pragma unroll
        for (int j = 0; j < 4; ++j) {
#pragma unroll
            for (int hlf = 0; hlf < 2; ++hlf) {
                int jj = 2 * j + hlf;
                int idx = (h * Dn + d0 + jj) * Dn + e;
                nA2[j][hlf] = -DTc * expf(OW[idx]);
                omc2[j][hlf] = 1.0f - 1.0f / (1.0f + expf(-OD[idx]));
            }
        }
        const v2f dt2 = {DTc, DTc};

        if (c > 0) {
            // A = [[1+DT*nA, DT*omc],[nA, omc]]; A^L by packed squaring.
            v2f m00[4], m01[4], m10[4], m11[4];
#pragma unroll
            for (int j = 0; j < 4; ++j) {
                m00[j] = vfma(dt2, nA2[j], (v2f)1.0f);
                m01[j] = dt2 * omc2[j];
                m10[j] = nA2[j];
                m11[j] = omc2[j];
            }
            for (int pw = 1; pw < L; pw <<= 1) {
#pragma unroll
                for (int j = 0; j < 4; ++j) {
                    v2f n00 = vfma(m00[j], m00[j], m01[j] * m10[j]);
                    v2f n01 = vfma(m00[j], m01[j], m01[j] * m11[j]);
                    v2f n10 = vfma(m10[j], m00[j], m11[j] * m10[j]);
                    v2f n11 = vfma(m10[j], m01[j], m11[j] * m11[j]);
                    m00[j] = n00; m01[j] = n01; m10[j] = n10; m11[j] = n11;
                }
            }
            for (int i = 0; i < c; ++i) {
                const float4* cw = (const float4*)wsBase(i);
#pragma unroll
                for (int j = 0; j < 4; ++j) {
                    float4 w = cw[j];
                    v2f cy = {w.x, w.y};
                    v2f cz = {w.z, w.w};
                    v2f ny = vfma(m00[j], y2[j], vfma(m01[j], z2[j], cy));
                    v2f nz = vfma(m10[j], y2[j], vfma(m11[j], z2[j], cz));
                    y2[j] = ny; z2[j] = nz;
                }
            }
        }

        stage(0, t0);
        __syncthreads();
        for (int ti = 0; ti < nT; ++ti) {
            int cur = ti & 1;
            if (ti + 1 < nT) stage(cur ^ 1, t0 + (ti + 1) * TILE);
            float* ops = op + (size_t)(t0 + ti * TILE) * TS;
#pragma unroll 8
            for (int s = 0; s < TILE; ++s) {
                const float4* kr = (const float4*)&sK[cur][s][d0];
                float4 ka = kr[0], kb = kr[1];
                float vv = sV[cur][s][el];
                float bb = sB[cur][s];
                float bv = (DTc * bb) * vv;
                v2f bv2 = {bv, bv};
                v2f kk[4] = {{ka.x, ka.y}, {ka.z, ka.w}, {kb.x, kb.y}, {kb.z, kb.w}};
#pragma unroll
                for (int j = 0; j < 4; ++j) {
                    z2[j] = vfma(omc2[j], z2[j], vfma(nA2[j], y2[j], bv2 * kk[j]));
                    y2[j] = vfma(dt2, z2[j], y2[j]);
                }
                {
                    const float4* qr = (const float4*)&sQ[cur][s][d0];
                    float4 qa = qr[0], qb = qr[1];
                    v2f qq[4] = {{qa.x, qa.y}, {qa.z, qa.w}, {qb.x, qb.y}, {qb.z, qb.w}};
                    v2f pp = (v2f)0.0f;
#pragma unroll
                    for (int j = 0; j < 4; ++j) pp = vfma(qq[j], y2[j], pp);
                    float p = pp[0] + pp[1];
                    p = dpp_add<0xB1>(p);   // quad_perm xor1 (exact)
                    p = dpp_add<0x4E>(p);   // quad_perm xor2 (exact)
                    p += __shfl_xor(p, 4);  // cross-quad (proven)
                    if (wlane) *ops = p * 0.125f; // scale = D^-0.5
                    ops += TS;
                }
            }
            __syncthreads();
        }
    }
}

extern "C" void kernel_launch(void* const* d_in, const int* in_sizes, int n_in,
                              void* d_out, int out_size, void* d_ws, size_t ws_size,
                              hipStream_t stream) {
    const float* q  = (const float*)d_in[0];
    const float* k  = (const float*)d_in[1];
    const float* v  = (const float*)d_in[2];
    const float* bt = (const float*)d_in[3];
    const float* ow = (const float*)d_in[4];
    const float* od = (const float*)d_in[5];
    float* out = (float*)d_out;
    float* ws = (float*)d_ws;

    const size_t chunkBytes = (size_t)128 * 2 * 4096 * sizeof(float); // 4 MiB

    if (ws_size >= 7 * chunkBytes) {
        // NC=8: L1 = eigen chunks 0..6 (1792 blocks);
        //       L2 = chunks 0..7 (2048 blocks = 2 exact residency phases).
        hipLaunchKernelGGL((linoss_k<8, 0>), dim3(1792), dim3(256), 0, stream,
                           q, k, v, bt, ow, od, out, ws);
        hipLaunchKernelGGL((linoss_k<8, 1>), dim3(2048), dim3(256), 0, stream,
                           q, k, v, bt, ow, od, out, ws);
    } else if (ws_size >= chunkBytes) {
        // NC=2: L1 = eigen chunk 0; L2 = chunks 0,1.
        hipLaunchKernelGGL((linoss_k<2, 0>), dim3(256), dim3(256), 0, stream,
                           q, k, v, bt, ow, od, out, ws);
        hipLaunchKernelGGL((linoss_k<2, 1>), dim3(512), dim3(256), 0, stream,
                           q, k, v, bt, ow, od, out, ws);
    } else {
        // NC=1: single full direct sweep (c=0 -> no prefix, dot, no ws).
        hipLaunchKernelGGL((linoss_k<1, 1>), dim3(256), dim3(256), 0, stream,
                           q, k, v, bt, ow, od, out, ws);
    }
}

// Round 21
// 262.838 us; speedup vs baseline: 1.0138x; 1.0138x over previous
//
#include <hip/hip_runtime.h>

// LinOSS: damped-oscillator linear SSM scan. B=8, T=2048, H=16, D=64.
//   s = 1-sigmoid(osc_damp); a = DT*exp(osc_w)
//   z' = s*z - a*y + w,  w = DT*beta*k[d]*v[e];  y' = y + DT*z'
//   out = (1/8) q . y
//
// FINAL (R19 revert): two-pass chunk-parallel, NC=8.
//   L1 chunks 0..6 (c0 direct+dot, else eigen 3-op/elem), all store ws;
//   L2 chunks 1..7 prefix (A^L packed squaring) + direct + dot.
// Packed dual-f32 via ext_vector_type(2) + __builtin_elementwise_fma.
// LDS-DMA staging (global_load_lds w16), double-buffered TILE=16.
// DPP quad_perm + shfl_xor(4) dot-reduction. XCD-aware block swizzle.
// R20's rebalance (L2=chunks 0..7) regressed 263->266: reverted.

constexpr float DTc = 0.01f;
constexpr int Tn = 2048, Hn = 16, Dn = 64;
constexpr int TS = Hn * Dn; // 1024 floats per t-step in q/k/v/out
constexpr int TILE = 16;

typedef float v2f __attribute__((ext_vector_type(2)));

__device__ __forceinline__ v2f vfma(v2f a, v2f b, v2f c) {
    return __builtin_elementwise_fma(a, b, c);
}

typedef const __attribute__((address_space(1))) void* as1_cvp;
typedef __attribute__((address_space(3))) void* as3_vp;

__device__ __forceinline__ void gload_lds4(const float* g, float* lds) {
    __builtin_amdgcn_global_load_lds((as1_cvp)g, (as3_vp)lds, 4, 0, 0);
}
__device__ __forceinline__ void gload_lds16(const float* g, float* lds) {
    __builtin_amdgcn_global_load_lds((as1_cvp)g, (as3_vp)lds, 16, 0, 0);
}

template<int CTRL>
__device__ __forceinline__ float dpp_add(float x) {
    int yi = __builtin_amdgcn_update_dpp(0, __float_as_int(x), CTRL, 0xF, 0xF, true);
    return x + __int_as_float(yi);
}

// MODE 0 (L1): c = blk>>8 in [0, NC-2]; c==0 direct+dot, c>0 eigen; store ws.
// MODE 1 (L2): c = c0 + (blk>>8); prefix-combine; direct+dot; no ws store.
template<int NC, int MODE>
__global__ __launch_bounds__(256, 4)
void linoss_k(const float* __restrict__ Q, const float* __restrict__ K,
              const float* __restrict__ V, const float* __restrict__ Bt,
              const float* __restrict__ OW, const float* __restrict__ OD,
              float* __restrict__ Out, float* __restrict__ WS, int c0) {
    constexpr int L = Tn / NC;

    __shared__ float sK[2][TILE][64];
    __shared__ float sQ[2][TILE][64];
    __shared__ float sV[2][TILE][32];
    __shared__ float sB[2][TILE];

    int blk = blockIdx.x;
    int c = (MODE == 0) ? (blk >> 8) : (c0 + (blk >> 8));
    bool doQ = (MODE == 1) || (c == 0);
    int sl = blk & 255;
    // XCD-aware decode: both e-halves of the same (b,h) on one XCD.
    int xcd = sl & 7, slot = sl >> 3;
    int ec = slot & 1;
    int bh = ((slot >> 1) << 3) | xcd;
    int b = bh >> 4, h = bh & 15;

    int tid = threadIdx.x;
    int dgrp = tid & 7;
    int el = tid >> 3;
    int e = ec * 32 + el;
    int d0 = dgrp * 8;
    int wv = tid >> 6;
    int ln = tid & 63;

    v2f y2[4], z2[4];
#pragma unroll
    for (int j = 0; j < 4; ++j) { y2[j] = (v2f)0.0f; z2[j] = (v2f)0.0f; }

    // per-(c,bh,ec) ws tile; quad j layout: {y[2j], y[2j+1], z[2j], z[2j+1]}
    auto wsBase = [&](int ci) {
        return WS + (((size_t)ci * 128 + bh) * 2 + ec) * 4096 + (size_t)tid * 16;
    };

    size_t bhOff = (size_t)b * Tn * TS + (size_t)h * Dn;
    const float* kb0 = K + bhOff;
    const float* qb0 = Q + bhOff;
    const float* vb0 = V + bhOff + ec * 32;
    const float* bb0 = Bt + (size_t)b * Tn * Hn + h;
    float* op = Out + bhOff + e;
    bool wlane = (dgrp == 0);

    int t0 = c * L;

    auto stage = [&](int buf, int tt0) {
        {
            int row = 4 * wv + (ln >> 4);
            gload_lds16(kb0 + (size_t)(tt0 + row) * TS + (ln & 15) * 4, &sK[buf][4 * wv][0]);
        }
        if (doQ) {
            int row = 4 * wv + (ln >> 4);
            gload_lds16(qb0 + (size_t)(tt0 + row) * TS + (ln & 15) * 4, &sQ[buf][4 * wv][0]);
        }
        if (wv < 2) {
            int row = 8 * wv + (ln >> 3);
            gload_lds16(vb0 + (size_t)(tt0 + row) * TS + (ln & 7) * 4, &sV[buf][8 * wv][0]);
        }
        if (wv == 2 && ln < 16)
            gload_lds4(bb0 + (size_t)(tt0 + ln) * Hn, &sB[buf][0]);
    };

    constexpr int nT = L / TILE;

    if (MODE == 0 && c > 0) {
        // ---------------- eigen state-only sweep (packed) ----------------
        v2f l12[4], l22[4], mt1[4], mt2[4];
        float l1s[8];
#pragma unroll
        for (int j = 0; j < 4; ++j) {
#pragma unroll
            for (int hlf = 0; hlf < 2; ++hlf) {
                int jj = 2 * j + hlf;
                int idx = (h * Dn + d0 + jj) * Dn + e;
                float aDT = DTc * expf(OW[idx]);
                float s = 1.0f - 1.0f / (1.0f + expf(-OD[idx]));
                float a00 = 1.0f - DTc * aDT, a11 = s;
                float a01 = DTc * s, a10 = -aDT;
                float tr = a00 + a11;
                float dmm = a00 - a11;
                float disc = fmaf(dmm, dmm, 4.0f * a01 * a10);
                float l1 = 0.5f * (tr + sqrtf(disc));
                l1s[jj] = l1;
                l12[j][hlf] = l1;
                l22[j][hlf] = s / l1;   // det = s exactly
            }
            mt1[j] = (v2f)0.0f; mt2[j] = (v2f)0.0f;
        }

        stage(0, t0);
        __syncthreads();
        for (int ti = 0; ti < nT; ++ti) {
            int cur = ti & 1;
            if (ti + 1 < nT) stage(cur ^ 1, t0 + (ti + 1) * TILE);
#pragma unroll 8
            for (int s = 0; s < TILE; ++s) {
                const float4* kr = (const float4*)&sK[cur][s][d0];
                float4 ka = kr[0], kb = kr[1];
                float vv = sV[cur][s][el];
                float bb = sB[cur][s];
                float bv = (DTc * bb) * vv;
                v2f bv2 = {bv, bv};
                v2f kk[4] = {{ka.x, ka.y}, {ka.z, ka.w}, {kb.x, kb.y}, {kb.z, kb.w}};
#pragma unroll
                for (int j = 0; j < 4; ++j) {
                    v2f w = bv2 * kk[j];
                    mt1[j] = vfma(l12[j], mt1[j], w);
                    mt2[j] = vfma(l22[j], mt2[j], w);
                }
            }
            __syncthreads();
        }

        // back-transform to (y,z), packed result
#pragma unroll
        for (int j = 0; j < 4; ++j) {
#pragma unroll
            for (int hlf = 0; hlf < 2; ++hlf) {
                int jj = 2 * j + hlf;
                int idx = (h * Dn + d0 + jj) * Dn + e;
                float aDT = DTc * expf(OW[idx]);
                float s = 1.0f - 1.0f / (1.0f + expf(-OD[idx]));
                float a00 = 1.0f - DTc * aDT, a11 = s;
                float a01 = DTc * s, a10 = -aDT;
                float l1 = l1s[jj], l2 = s / l1;
                float b1 = a01 / (l1 - a11);
                float b2 = (l2 - a00) / a10;
                float c1 = DTc + b1, c2 = DTc + b2;
                float rdb = 1.0f / (b2 - b1);
                float Y1 = b2 * c1 * rdb, Y2 = -b1 * c2 * rdb;
                float Z1 = -c1 * rdb, Z2 = c2 * rdb;
                float m1 = mt1[j][hlf], m2 = mt2[j][hlf];
                y2[j][hlf] = fmaf(Y1, m1, Y2 * m2);
                z2[j][hlf] = fmaf(Z1, m1, Z2 * m2);
            }
        }
    } else {
        // ---------------- direct sweep with dot (packed) ----------------
        v2f nA2[4], omc2[4];
#pragma unroll
        for (int j = 0; j < 4; ++j) {
#pragma unroll
            for (int hlf = 0; hlf < 2; ++hlf) {
                int jj = 2 * j + hlf;
                int idx = (h * Dn + d0 + jj) * Dn + e;
                nA2[j][hlf] = -DTc * expf(OW[idx]);
                omc2[j][hlf] = 1.0f - 1.0f / (1.0f + expf(-OD[idx]));
            }
        }
        const v2f dt2 = {DTc, DTc};

        if (MODE == 1 && c > 0) {
            // A = [[1+DT*nA, DT*omc],[nA, omc]]; A^L by packed squaring.
            v2f m00[4], m01[4], m10[4], m11[4];
#pragma unroll
            for (int j = 0; j < 4; ++j) {
                m00[j] = vfma(dt2, nA2[j], (v2f)1.0f);
                m01[j] = dt2 * omc2[j];
                m10[j] = nA2[j];
                m11[j] = omc2[j];
            }
            for (int pw = 1; pw < L; pw <<= 1) {
#pragma unroll
                for (int j = 0; j < 4; ++j) {
                    v2f n00 = vfma(m00[j], m00[j], m01[j] * m10[j]);
                    v2f n01 = vfma(m00[j], m01[j], m01[j] * m11[j]);
                    v2f n10 = vfma(m10[j], m00[j], m11[j] * m10[j]);
                    v2f n11 = vfma(m10[j], m01[j], m11[j] * m11[j]);
                    m00[j] = n00; m01[j] = n01; m10[j] = n10; m11[j] = n11;
                }
            }
            for (int i = 0; i < c; ++i) {
                const float4* cw = (const float4*)wsBase(i);
#pragma unroll
                for (int j = 0; j < 4; ++j) {
                    float4 w = cw[j];
                    v2f cy = {w.x, w.y};
                    v2f cz = {w.z, w.w};
                    v2f ny = vfma(m00[j], y2[j], vfma(m01[j], z2[j], cy));
                    v2f nz = vfma(m10[j], y2[j], vfma(m11[j], z2[j], cz));
                    y2[j] = ny; z2[j] = nz;
                }
            }
        }

        stage(0, t0);
        __syncthreads();
        for (int ti = 0; ti < nT; ++ti) {
            int cur = ti & 1;
            if (ti + 1 < nT) stage(cur ^ 1, t0 + (ti + 1) * TILE);
            float* ops = op + (size_t)(t0 + ti * TILE) * TS;
#pragma unroll 8
            for (int s = 0; s < TILE; ++s) {
                const float4* kr = (const float4*)&sK[cur][s][d0];
                float4 ka = kr[0], kb = kr[1];
                float vv = sV[cur][s][el];
                float bb = sB[cur][s];
                float bv = (DTc * bb) * vv;
                v2f bv2 = {bv, bv};
                v2f kk[4] = {{ka.x, ka.y}, {ka.z, ka.w}, {kb.x, kb.y}, {kb.z, kb.w}};
#pragma unroll
                for (int j = 0; j < 4; ++j) {
                    z2[j] = vfma(omc2[j], z2[j], vfma(nA2[j], y2[j], bv2 * kk[j]));
                    y2[j] = vfma(dt2, z2[j], y2[j]);
                }
                if (doQ) {
                    const float4* qr = (const float4*)&sQ[cur][s][d0];
                    float4 qa = qr[0], qb = qr[1];
                    v2f qq[4] = {{qa.x, qa.y}, {qa.z, qa.w}, {qb.x, qb.y}, {qb.z, qb.w}};
                    v2f pp = (v2f)0.0f;
#pragma unroll
                    for (int j = 0; j < 4; ++j) pp = vfma(qq[j], y2[j], pp);
                    float p = pp[0] + pp[1];
                    p = dpp_add<0xB1>(p);   // quad_perm xor1 (exact)
                    p = dpp_add<0x4E>(p);   // quad_perm xor2 (exact)
                    p += __shfl_xor(p, 4);  // cross-quad (proven)
                    if (wlane) *ops = p * 0.125f; // scale = D^-0.5
                    ops += TS;
                }
            }
            __syncthreads();
        }
    }

    if (MODE == 0) {
        float4* cw = (float4*)wsBase(c);
#pragma unroll
        for (int j = 0; j < 4; ++j) {
            float4 w;
            w.x = y2[j][0]; w.y = y2[j][1];
            w.z = z2[j][0]; w.w = z2[j][1];
            cw[j] = w;
        }
    }
}

extern "C" void kernel_launch(void* const* d_in, const int* in_sizes, int n_in,
                              void* d_out, int out_size, void* d_ws, size_t ws_size,
                              hipStream_t stream) {
    const float* q  = (const float*)d_in[0];
    const float* k  = (const float*)d_in[1];
    const float* v  = (const float*)d_in[2];
    const float* bt = (const float*)d_in[3];
    const float* ow = (const float*)d_in[4];
    const float* od = (const float*)d_in[5];
    float* out = (float*)d_out;
    float* ws = (float*)d_ws;

    const size_t chunkBytes = (size_t)128 * 2 * 4096 * sizeof(float); // 4 MiB

    if (ws_size >= 7 * chunkBytes) {
        // NC=8: L1 = chunks 0..6 (c0 direct+dot, 1..6 eigen); L2 = chunks 1..7.
        hipLaunchKernelGGL((linoss_k<8, 0>), dim3(1792), dim3(256), 0, stream,
                           q, k, v, bt, ow, od, out, ws, 0);
        hipLaunchKernelGGL((linoss_k<8, 1>), dim3(1792), dim3(256), 0, stream,
                           q, k, v, bt, ow, od, out, ws, 1);
    } else if (ws_size >= chunkBytes) {
        // NC=2: L1 = chunk 0 (direct+dot+ws); L2 = chunk 1.
        hipLaunchKernelGGL((linoss_k<2, 0>), dim3(256), dim3(256), 0, stream,
                           q, k, v, bt, ow, od, out, ws, 0);
        hipLaunchKernelGGL((linoss_k<2, 1>), dim3(256), dim3(256), 0, stream,
                           q, k, v, bt, ow, od, out, ws, 1);
    } else {
        // NC=1: single full sweep (c0=0 -> no prefix, q-dot, no ws).
        hipLaunchKernelGGL((linoss_k<1, 1>), dim3(256), dim3(256), 0, stream,
                           q, k, v, bt, ow, od, out, ws, 0);
    }
}